// Round 3
// baseline (263.827 us; speedup 1.0000x reference)
//
#include <hip/hip_runtime.h>
#include <hip/hip_bf16.h>
#include <math.h>

#define WAVE 64
#define MAX_CHUNKS 128   // S=8192 -> 128 chunks of 64 tokens

// ---------------- K1: softmax + top1/top2 + per-chunk expert histogram ----
// One 256-thread block (4 waves) per 64-token chunk; each wave handles 16
// tokens serially, lane e = expert e. Histogram via LDS atomics (count sums
// are order-independent -> deterministic).
__global__ void __launch_bounds__(256)
softmax_top2_hist(const float* __restrict__ x,
                  int* __restrict__ top1,
                  int* __restrict__ top2,
                  float* __restrict__ w1,
                  float* __restrict__ w2,
                  int* __restrict__ hist1,
                  int* __restrict__ hist2) {
    __shared__ int lh1[64], lh2[64];
    const int c    = blockIdx.x;
    const int wid  = threadIdx.x >> 6;
    const int lane = threadIdx.x & 63;

    if (threadIdx.x < 64) { lh1[threadIdx.x] = 0; lh2[threadIdx.x] = 0; }
    __syncthreads();

    #pragma unroll 4
    for (int k = 0; k < 16; ++k) {
        const int s = c * 64 + wid * 16 + k;
        const float v = x[(size_t)s * 64 + lane];

        // argmax, lowest-index tiebreak (matches jnp.argmax)
        float bv = v; int bi = lane;
        #pragma unroll
        for (int off = 32; off >= 1; off >>= 1) {
            float ov = __shfl_xor(bv, off, WAVE);
            int   oi = __shfl_xor(bi, off, WAVE);
            if (ov > bv || (ov == bv && oi < bi)) { bv = ov; bi = oi; }
        }
        const float m = bv;
        const int t1 = bi;

        // fp32 softmax
        float e = expf(v - m);
        float sum = e;
        #pragma unroll
        for (int off = 32; off >= 1; off >>= 1) sum += __shfl_xor(sum, off, WAVE);
        const float p = e / sum;

        // second argmax with top1 masked out
        float v2 = (lane == t1) ? -INFINITY : v;
        float bv2 = v2; int bi2 = lane;
        #pragma unroll
        for (int off = 32; off >= 1; off >>= 1) {
            float ov = __shfl_xor(bv2, off, WAVE);
            int   oi = __shfl_xor(bi2, off, WAVE);
            if (ov > bv2 || (ov == bv2 && oi < bi2)) { bv2 = ov; bi2 = oi; }
        }
        const int t2 = bi2;

        const float p1 = __shfl(p, t1, WAVE);
        const float p2 = __shfl(p, t2, WAVE);

        if (lane == 0) {
            top1[s] = t1; top2[s] = t2;
            w1[s] = p1;   w2[s] = p2;
            atomicAdd(&lh1[t1], 1);
            atomicAdd(&lh2[t2], 1);
        }
    }
    __syncthreads();
    if (threadIdx.x < 64) {
        hist1[c * 64 + threadIdx.x] = lh1[threadIdx.x];
        hist2[c * 64 + threadIdx.x] = lh2[threadIdx.x];
    }
}

// ---------------- K2: scan + stable ranks + sparse scatter ----------------
// Single 1024-thread block. Phase a: 128 threads scan the per-chunk
// histograms (exclusive) into LDS. Phase b: 16 waves sweep chunks; each
// lane = one token of the chunk, within-chunk stable count via shfl loop,
// then scatter <=2 outputs per token into the (already-zeroed) output.
__global__ void __launch_bounds__(1024)
scan_rank_scatter(const int* __restrict__ top1,
                  const int* __restrict__ top2,
                  const float* __restrict__ w1,
                  const float* __restrict__ w2,
                  const int* __restrict__ hist1,
                  const int* __restrict__ hist2,
                  float* __restrict__ out,
                  int nchunks, int CAP, size_t secoff) {
    __shared__ int b1[MAX_CHUNKS * 64];
    __shared__ int b2[MAX_CHUNKS * 64];
    __shared__ int tot1[64];
    const int tid = threadIdx.x;

    if (tid < 64) {
        int r = 0;
        for (int c = 0; c < nchunks; ++c) { b1[c * 64 + tid] = r; r += hist1[c * 64 + tid]; }
        tot1[tid] = r;   // sum(mask1, axis=0) pre-drop: offset for rank2
    } else if (tid < 128) {
        const int e = tid - 64;
        int r = 0;
        for (int c = 0; c < nchunks; ++c) { b2[c * 64 + e] = r; r += hist2[c * 64 + e]; }
    }
    __syncthreads();

    const int wid = tid >> 6, lane = tid & 63;
    const int nw = blockDim.x >> 6;
    for (int c = wid; c < nchunks; c += nw) {
        const int s = c * 64 + lane;
        const int t1 = top1[s];
        const int t2 = top2[s];

        int cnt1 = 0, cnt2 = 0;
        #pragma unroll 8
        for (int j = 0; j < 64; ++j) {
            const int o1 = __shfl(t1, j, WAVE);
            const int o2 = __shfl(t2, j, WAVE);
            cnt1 += (o1 == t1) && (j < lane);
            cnt2 += (o2 == t2) && (j < lane);
        }

        const int r1 = b1[c * 64 + t1] + cnt1;
        const int r2 = b2[c * 64 + t2] + cnt2 + tot1[t2];

        if (r1 < CAP) {
            const size_t idx = ((size_t)s * 64 + t1) * CAP + r1;
            out[idx] = w1[s];
            out[secoff + idx] = 1.0f;
        }
        if (r2 < CAP) {
            const size_t idx = ((size_t)s * 64 + t2) * CAP + r2;
            out[idx] = w2[s];
            out[secoff + idx] = 1.0f;
        }
    }
}

extern "C" void kernel_launch(void* const* d_in, const int* in_sizes, int n_in,
                              void* d_out, int out_size, void* d_ws, size_t ws_size,
                              hipStream_t stream) {
    const float* x = (const float*)d_in[0];
    float* out = (float*)d_out;

    const int E = 64;
    const int S = in_sizes[0] / E;            // 8192
    int cap = (int)(2.0 * S / E);
    cap += cap % 2;
    if (cap < 4) cap = 4;                     // 256

    const int nchunks = S / 64;               // 128 (== MAX_CHUNKS)
    const size_t secoff = (size_t)S * E * cap;

    // workspace layout
    char* w = (char*)d_ws;
    int*   top1  = (int*)w;   w += (size_t)S * 4;
    int*   top2  = (int*)w;   w += (size_t)S * 4;
    float* w1    = (float*)w; w += (size_t)S * 4;
    float* w2    = (float*)w; w += (size_t)S * 4;
    int*   hist1 = (int*)w;   w += (size_t)nchunks * 64 * 4;
    int*   hist2 = (int*)w;   w += (size_t)nchunks * 64 * 4;

    // 1) zero the dense output — the roofline cost (runtime fill ~6.5 TB/s)
    hipMemsetAsync(d_out, 0, (size_t)out_size * sizeof(float), stream);

    // 2) softmax + top2 + per-chunk histogram (one block per 64-token chunk)
    softmax_top2_hist<<<nchunks, 256, 0, stream>>>(x, top1, top2, w1, w2,
                                                   hist1, hist2);

    // 3) scan + ranks + sparse scatter (single block; after memset)
    scan_rank_scatter<<<1, 1024, 0, stream>>>(top1, top2, w1, w2,
                                              hist1, hist2, out,
                                              nchunks, cap, secoff);
}

// Round 4
// 255.546 us; speedup vs baseline: 1.0324x; 1.0324x over previous
//
#include <hip/hip_runtime.h>
#include <hip/hip_bf16.h>
#include <math.h>

#define WAVE 64

// ---------------- K1: per-token softmax + top1/top2 ----------------
// One 64-lane wave per token; lane e holds logit[s][e].
__global__ void __launch_bounds__(256)
router_softmax_top2(const float* __restrict__ x,
                    int* __restrict__ top1,
                    int* __restrict__ top2,
                    float* __restrict__ w1,
                    float* __restrict__ w2,
                    int S) {
    const int wavesPerBlock = blockDim.x >> 6;
    const int wid  = threadIdx.x >> 6;
    const int lane = threadIdx.x & 63;
    const int s = blockIdx.x * wavesPerBlock + wid;
    if (s >= S) return;

    float v = x[(size_t)s * 64 + lane];

    // argmax with lowest-index tiebreak (matches jnp.argmax)
    float bv = v; int bi = lane;
    #pragma unroll
    for (int off = 32; off >= 1; off >>= 1) {
        float ov = __shfl_xor(bv, off, WAVE);
        int   oi = __shfl_xor(bi, off, WAVE);
        if (ov > bv || (ov == bv && oi < bi)) { bv = ov; bi = oi; }
    }
    const float m = bv;
    const int t1 = bi;

    // fp32 softmax
    float e = expf(v - m);
    float sum = e;
    #pragma unroll
    for (int off = 32; off >= 1; off >>= 1) sum += __shfl_xor(sum, off, WAVE);
    const float p = e / sum;

    // second argmax with top1 masked out
    float v2 = (lane == t1) ? -INFINITY : v;
    float bv2 = v2; int bi2 = lane;
    #pragma unroll
    for (int off = 32; off >= 1; off >>= 1) {
        float ov = __shfl_xor(bv2, off, WAVE);
        int   oi = __shfl_xor(bi2, off, WAVE);
        if (ov > bv2 || (ov == bv2 && oi < bi2)) { bv2 = ov; bi2 = oi; }
    }
    const int t2 = bi2;

    const float p1 = __shfl(p, t1, WAVE);
    const float p2 = __shfl(p, t2, WAVE);

    if (lane == 0) {
        top1[s] = t1; top2[s] = t2;
        w1[s] = p1;   w2[s] = p2;
    }
}

// ---------------- K2: per-expert ballot rank sweep ----------------
// Wave w = expert w (64 waves total). Sweeps all tokens in 64-token chunks;
// cumsum-rank = running count + popcount of earlier lanes matching. Loads
// are independent across iterations -> compiler pipelines them (no serial
// global-latency chain, unlike a 1-thread-per-expert scan).
__global__ void __launch_bounds__(256)
rank_ballot(const int* __restrict__ top1,
            const int* __restrict__ top2,
            int* __restrict__ pos1,     // e*CAP+rank1 (or -1 if dropped)
            int* __restrict__ r2rel,    // rank2 before +total1 offset
            int* __restrict__ total1,   // per-expert top-1 count (pre-drop)
            int nchunks, int CAP) {
    const int e    = (blockIdx.x * blockDim.x + threadIdx.x) >> 6; // expert id
    const int lane = threadIdx.x & 63;
    const unsigned long long ltmask = (1ull << lane) - 1ull;

    int run1 = 0, run2 = 0;
    #pragma unroll 8
    for (int c = 0; c < nchunks; ++c) {
        const int s  = c * 64 + lane;
        const int t1 = top1[s];
        const int t2 = top2[s];
        const unsigned long long m1 = __ballot(t1 == e);
        const unsigned long long m2 = __ballot(t2 == e);
        if (t1 == e) {
            const int r = run1 + __popcll(m1 & ltmask);
            pos1[s] = (r < CAP) ? (e * CAP + r) : -1;
        }
        if (t2 == e) {
            r2rel[s] = run2 + __popcll(m2 & ltmask);
        }
        run1 += __popcll(m1);
        run2 += __popcll(m2);
    }
    if (lane == 0) total1[e] = run1;
}

// ---------------- K3: sparse scatter into zeroed output ----------------
__global__ void __launch_bounds__(256)
scatter(const int* __restrict__ top2,
        const int* __restrict__ pos1,
        const int* __restrict__ r2rel,
        const int* __restrict__ total1,
        const float* __restrict__ w1,
        const float* __restrict__ w2,
        float* __restrict__ out,
        int CAP, int ROW, size_t secoff, int S) {
    const int s = blockIdx.x * blockDim.x + threadIdx.x;
    if (s >= S) return;

    const int p1 = pos1[s];
    if (p1 >= 0) {
        const size_t idx = (size_t)s * ROW + p1;
        out[idx] = w1[s];
        out[secoff + idx] = 1.0f;
    }
    const int t2 = top2[s];
    const int r2 = r2rel[s] + total1[t2];   // += sum(mask1) offset
    if (r2 < CAP) {
        const size_t idx = (size_t)s * ROW + t2 * CAP + r2;
        out[idx] = w2[s];
        out[secoff + idx] = 1.0f;
    }
}

extern "C" void kernel_launch(void* const* d_in, const int* in_sizes, int n_in,
                              void* d_out, int out_size, void* d_ws, size_t ws_size,
                              hipStream_t stream) {
    const float* x = (const float*)d_in[0];
    float* out = (float*)d_out;

    const int E = 64;
    const int S = in_sizes[0] / E;            // 8192
    int cap = (int)(2.0 * S / E);
    cap += cap % 2;
    if (cap < 4) cap = 4;                     // 256

    const int nchunks = S / 64;               // 128
    const int ROW = E * cap;                  // 16384
    const size_t secoff = (size_t)S * ROW;

    // workspace layout
    char* w = (char*)d_ws;
    int*   top1   = (int*)w;   w += (size_t)S * 4;
    int*   top2   = (int*)w;   w += (size_t)S * 4;
    float* w1     = (float*)w; w += (size_t)S * 4;
    float* w2     = (float*)w; w += (size_t)S * 4;
    int*   pos1   = (int*)w;   w += (size_t)S * 4;
    int*   r2rel  = (int*)w;   w += (size_t)S * 4;
    int*   total1 = (int*)w;   w += 64 * 4;

    // 1) softmax + top2 (one wave per token)
    {
        const int wavesPerBlock = 4;
        const int blocks = (S + wavesPerBlock - 1) / wavesPerBlock;
        router_softmax_top2<<<blocks, wavesPerBlock * 64, 0, stream>>>(
            x, top1, top2, w1, w2, S);
    }

    // 2) per-expert ballot ranks (64 waves = 16 blocks x 256)
    rank_ballot<<<16, 256, 0, stream>>>(top1, top2, pos1, r2rel, total1,
                                        nchunks, cap);

    // 3) zero the dense output — the roofline cost (runtime fill ~6.5 TB/s)
    hipMemsetAsync(d_out, 0, (size_t)out_size * sizeof(float), stream);

    // 4) sparse scatter (<=2 nonzeros per token)
    scatter<<<(S + 255) / 256, 256, 0, stream>>>(top2, pos1, r2rel, total1,
                                                 w1, w2, out,
                                                 cap, ROW, secoff, S);
}

// Round 5
// 251.992 us; speedup vs baseline: 1.0470x; 1.0141x over previous
//
#include <hip/hip_runtime.h>
#include <hip/hip_bf16.h>
#include <math.h>

#define WAVE 64

// ---------------- K1: per-token softmax + top1/top2 ----------------
// One 64-lane wave per token; lane e holds logit[s][e]. Packs the result
// as int4{t1, t2, bits(w1), bits(w2)} -> one 16B store per token.
__global__ void __launch_bounds__(256)
router_softmax_top2(const float* __restrict__ x,
                    int4* __restrict__ tok,
                    int S) {
    const int wavesPerBlock = blockDim.x >> 6;
    const int wid  = threadIdx.x >> 6;
    const int lane = threadIdx.x & 63;
    const int s = blockIdx.x * wavesPerBlock + wid;
    if (s >= S) return;

    float v = x[(size_t)s * 64 + lane];

    // argmax with lowest-index tiebreak (matches jnp.argmax)
    float bv = v; int bi = lane;
    #pragma unroll
    for (int off = 32; off >= 1; off >>= 1) {
        float ov = __shfl_xor(bv, off, WAVE);
        int   oi = __shfl_xor(bi, off, WAVE);
        if (ov > bv || (ov == bv && oi < bi)) { bv = ov; bi = oi; }
    }
    const float m = bv;
    const int t1 = bi;

    // fp32 softmax
    float e = expf(v - m);
    float sum = e;
    #pragma unroll
    for (int off = 32; off >= 1; off >>= 1) sum += __shfl_xor(sum, off, WAVE);
    const float p = e / sum;

    // second argmax with top1 masked out
    float v2 = (lane == t1) ? -INFINITY : v;
    float bv2 = v2; int bi2 = lane;
    #pragma unroll
    for (int off = 32; off >= 1; off >>= 1) {
        float ov = __shfl_xor(bv2, off, WAVE);
        int   oi = __shfl_xor(bi2, off, WAVE);
        if (ov > bv2 || (ov == bv2 && oi < bi2)) { bv2 = ov; bi2 = oi; }
    }
    const int t2 = bi2;

    const float p1 = __shfl(p, t1, WAVE);
    const float p2 = __shfl(p, t2, WAVE);

    if (lane == 0) {
        tok[s] = make_int4(t1, t2, __float_as_int(p1), __float_as_int(p2));
    }
}

// ---------------- K2: per-expert ballot ranks + sparse scatter ----------
// 64 waves total, wave = expert e. cumsum-rank via ballot+popcount:
//   rank = running per-expert count + #earlier lanes in this chunk matching.
// Sweep A handles top-1 (and yields total1[e] = full top-1 count of e);
// sweep B handles top-2 with the +total1[e] offset (rank2 += sum(mask1)).
// Output buffer was already zeroed, so only <=2 slots/token are written.
__global__ void __launch_bounds__(256)
rank_scatter(const int4* __restrict__ tok,
             float* __restrict__ out,
             int nchunks, int CAP, int ROW, size_t secoff) {
    const int e    = (blockIdx.x * blockDim.x + threadIdx.x) >> 6; // expert id
    const int lane = threadIdx.x & 63;
    const unsigned long long lt = (1ull << lane) - 1ull;

    int run1 = 0;
    #pragma unroll 4
    for (int c = 0; c < nchunks; ++c) {
        const int4 t = tok[c * 64 + lane];
        const unsigned long long m1 = __ballot(t.x == e);
        if (t.x == e) {
            const int r = run1 + __popcll(m1 & lt);
            if (r < CAP) {
                const size_t idx = (size_t)(c * 64 + lane) * ROW + e * CAP + r;
                out[idx] = __int_as_float(t.z);
                out[secoff + idx] = 1.0f;
            }
        }
        run1 += __popcll(m1);
    }

    int run2 = 0;
    #pragma unroll 4
    for (int c = 0; c < nchunks; ++c) {
        const int4 t = tok[c * 64 + lane];
        const unsigned long long m2 = __ballot(t.y == e);
        if (t.y == e) {
            const int r = run2 + __popcll(m2 & lt) + run1;  // +total1[e]
            if (r < CAP) {
                const size_t idx = (size_t)(c * 64 + lane) * ROW + e * CAP + r;
                out[idx] = __int_as_float(t.w);
                out[secoff + idx] = 1.0f;
            }
        }
        run2 += __popcll(m2);
    }
}

extern "C" void kernel_launch(void* const* d_in, const int* in_sizes, int n_in,
                              void* d_out, int out_size, void* d_ws, size_t ws_size,
                              hipStream_t stream) {
    const float* x = (const float*)d_in[0];
    float* out = (float*)d_out;

    const int E = 64;
    const int S = in_sizes[0] / E;            // 8192
    int cap = (int)(2.0 * S / E);
    cap += cap % 2;
    if (cap < 4) cap = 4;                     // 256

    const int nchunks = S / 64;               // 128
    const int ROW = E * cap;                  // 16384
    const size_t secoff = (size_t)S * ROW;

    int4* tok = (int4*)d_ws;                  // S * 16 bytes

    // 1) zero the dense output first — the roofline term
    hipMemsetAsync(d_out, 0, (size_t)out_size * sizeof(float), stream);

    // 2) softmax + top2, packed token records (one wave per token)
    {
        const int wavesPerBlock = 4;
        const int blocks = (S + wavesPerBlock - 1) / wavesPerBlock;
        router_softmax_top2<<<blocks, wavesPerBlock * 64, 0, stream>>>(x, tok, S);
    }

    // 3) ballot ranks + sparse scatter (64 waves = 16 blocks x 256)
    rank_scatter<<<16, 256, 0, stream>>>(tok, out, nchunks, cap, ROW, secoff);
}